// Round 7
// baseline (457.413 us; speedup 1.0000x reference)
//
#include <hip/hip_runtime.h>

#define SCALE 0.17677669529663687f

typedef __attribute__((ext_vector_type(8))) short bf16x8;
typedef __attribute__((ext_vector_type(4))) float f32x4;

__device__ __forceinline__ unsigned short f2bf(float f) {
    unsigned u = __float_as_uint(f);
    u += 0x7FFFu + ((u >> 16) & 1u);   // round-to-nearest-even
    return (unsigned short)(u >> 16);
}
__device__ __forceinline__ float bf2f(unsigned short s) {
    return __uint_as_float(((unsigned)s) << 16);
}
// pack two f32 -> u32 of 2 bf16 (lo = a, hi = b), RNE, pure C (NOTE: inline-asm
// v_cvt_pk_bf16_f32 produced NaNs in round 4 -- do not reintroduce without isolation)
__device__ __forceinline__ unsigned pk2c(float a, float b) {
    return (unsigned)f2bf(a) | ((unsigned)f2bf(b) << 16);
}

// ---------------- weights -> bf16 ----------------
__global__ __launch_bounds__(256) void wconv_kernel(
        const float* __restrict__ w_qkv, const float* __restrict__ w_out,
        unsigned short* __restrict__ wq, unsigned short* __restrict__ wo) {
    int idx = blockIdx.x * 256 + threadIdx.x;
    if (idx < 196608) wq[idx] = f2bf(w_qkv[idx]);
    else if (idx < 262144) wo[idx - 196608] = f2bf(w_out[idx - 196608]);
}

// ---- k1a: QKV GEMM. block = 64 consecutive tokens, 256 threads (4 waves).
// A = wq channels (interleaved pair mapping), B = x-tile in LDS (N=tokens).
// qkv2 layout: [chunk c=ch/8][token][8 ch]  -> lane's D store = one chunk of one
// token = 16 B; 16 lrow-lanes = 256 B CONTIGUOUS per instruction. No RFO, no bounce.
// LDS: 32 KiB, x-tile 64 tok x 256 ch bf16, swizzled.
__global__ __launch_bounds__(256, 4) void qkv_gemm_kernel(
        const float* __restrict__ x, const unsigned short* __restrict__ wq,
        unsigned short* __restrict__ qkv2) {
    __shared__ unsigned char lds[32768];
    const int tid  = threadIdx.x;
    const int tb   = blockIdx.x << 6;      // 64 consecutive tokens
    const int b    = tb >> 14;
    const int hw0  = tb & 16383;
    const float* xb = x + (size_t)b * 4194304 + hw0;
    const int tok  = tid & 63;
    const int wave = tid >> 6;

    // stage x -> LDS bf16 [token][ch] swizzled. lane=token (coalesced 256B), pack 8ch -> b128.
    #pragma unroll
    for (int cg = 0; cg < 8; ++cg) {
        const int c0 = wave * 64 + cg * 8;
        float f[8];
        #pragma unroll
        for (int e = 0; e < 8; ++e) f[e] = xb[(size_t)(c0 + e) * 16384 + tok];
        unsigned u0 = pk2c(f[0], f[1]), u1 = pk2c(f[2], f[3]);
        unsigned u2 = pk2c(f[4], f[5]), u3 = pk2c(f[6], f[7]);
        const int slot = (c0 >> 3) ^ (tok & 7);
        *(uint4*)(lds + tok * 512 + (slot << 4)) = make_uint4(u0, u1, u2, u3);
    }
    __syncthreads();

    const int lane = tid & 63;
    const int lrow = lane & 15, lk = lane >> 4;

    for (int nb = 0; nb < 3; ++nb) {
        const int ch0 = nb * 256 + wave * 64;   // wave's 64-channel slice this pass
        f32x4 acc[4][4];                        // [tile 2p+m][nt]
        #pragma unroll
        for (int t4 = 0; t4 < 4; ++t4)
            #pragma unroll
            for (int nt = 0; nt < 4; ++nt)
                acc[t4][nt] = (f32x4){0.f, 0.f, 0.f, 0.f};
        #pragma unroll
        for (int k = 0; k < 8; ++k) {
            bf16x8 aw[4], bx[4];
            #pragma unroll
            for (int t4 = 0; t4 < 4; ++t4) {
                const int p = t4 >> 1, m = t4 & 1;
                const int row = ch0 + p * 32 + lrow * 2 + m;   // interleaved channel map
                aw[t4] = *(const bf16x8*)((const unsigned char*)wq +
                        (size_t)row * 512 + k * 64 + lk * 16);
            }
            #pragma unroll
            for (int nt = 0; nt < 4; ++nt) {
                int t = nt * 16 + lrow;
                int slot = (k * 4 + lk) ^ (t & 7);
                bx[nt] = *(const bf16x8*)(lds + t * 512 + (slot << 4));
            }
            #pragma unroll
            for (int t4 = 0; t4 < 4; ++t4)
                #pragma unroll
                for (int nt = 0; nt < 4; ++nt)
                    acc[t4][nt] = __builtin_amdgcn_mfma_f32_16x16x32_bf16(aw[t4], bx[nt], acc[t4][nt], 0, 0, 0);
        }
        // D: token = nt*16+lrow, lane's chunk = (ch0 + p*32 + lk*8)/8.
        // dword j = channels (2j from m=0 tile, 2j+1 from m=1 tile).
        #pragma unroll
        for (int nt = 0; nt < 4; ++nt) {
            const size_t tokg = tb + nt * 16 + lrow;
            #pragma unroll
            for (int p = 0; p < 2; ++p) {
                uint4 v;
                v.x = pk2c(acc[2 * p][nt][0], acc[2 * p + 1][nt][0]);
                v.y = pk2c(acc[2 * p][nt][1], acc[2 * p + 1][nt][1]);
                v.z = pk2c(acc[2 * p][nt][2], acc[2 * p + 1][nt][2]);
                v.w = pk2c(acc[2 * p][nt][3], acc[2 * p + 1][nt][3]);
                const int c = (ch0 >> 3) + p * 4 + lk;
                *(uint4*)(qkv2 + ((size_t)c * 131072 + tokg) * 8) = v;
            }
        }
    }
}

// ---- k1b: head-attention, no LDS. tid = h*32 + hf*16 + tl (16 tokens/block).
// qkv2 chunk-major: loads are 256-B contiguous per (h,hf) lane-group.
__global__ __launch_bounds__(256, 4) void attn_kernel(
        const unsigned short* __restrict__ qkv2, unsigned short* __restrict__ o_ws) {
    const int tid = threadIdx.x;
    const int h   = tid >> 5;
    const int hf  = (tid >> 4) & 1;
    const int tl  = tid & 15;
    const int tok = (blockIdx.x << 4) + tl;

    float q[16];
    #pragma unroll
    for (int jj = 0; jj < 2; ++jj) {
        const int c = h * 4 + hf * 2 + jj;
        bf16x8 v = *(const bf16x8*)(qkv2 + ((size_t)c * 131072 + tok) * 8);
        #pragma unroll
        for (int e = 0; e < 8; ++e) q[jj * 8 + e] = bf2f((unsigned short)v[e]);
    }
    float dots[8];
    #pragma unroll
    for (int g = 0; g < 8; ++g) {
        float acc = 0.f;
        #pragma unroll
        for (int jj = 0; jj < 2; ++jj) {
            const int c = 32 + g * 4 + hf * 2 + jj;
            bf16x8 v = *(const bf16x8*)(qkv2 + ((size_t)c * 131072 + tok) * 8);
            #pragma unroll
            for (int e = 0; e < 8; ++e) acc += q[jj * 8 + e] * bf2f((unsigned short)v[e]);
        }
        dots[g] = acc;
    }
    #pragma unroll
    for (int g = 0; g < 8; ++g)
        dots[g] = (dots[g] + __shfl_xor(dots[g], 16, 64)) * SCALE;
    float mx = dots[0];
    #pragma unroll
    for (int g = 1; g < 8; ++g) mx = fmaxf(mx, dots[g]);
    float sum = 0.f;
    #pragma unroll
    for (int g = 0; g < 8; ++g) { dots[g] = __expf(dots[g] - mx); sum += dots[g]; }
    const float inv = 1.f / sum;
    float o[16];
    #pragma unroll
    for (int d = 0; d < 16; ++d) o[d] = 0.f;
    #pragma unroll
    for (int g = 0; g < 8; ++g) {
        const float p = dots[g] * inv;
        #pragma unroll
        for (int jj = 0; jj < 2; ++jj) {
            const int c = 64 + g * 4 + hf * 2 + jj;
            bf16x8 v = *(const bf16x8*)(qkv2 + ((size_t)c * 131072 + tok) * 8);
            #pragma unroll
            for (int e = 0; e < 8; ++e) o[jj * 8 + e] += p * bf2f((unsigned short)v[e]);
        }
    }
    // mixing fold: out2[win][n'=h*8+r][c'=s*32 + hf*16 + jj*8 + e]
    const int bb2 = tok >> 14, rem = tok & 16383;
    const int himg = rem >> 7, wimg = rem & 127;
    const int ih = himg >> 3, r = himg & 7;
    const int iw = wimg >> 3, s = wimg & 7;
    const int win = (bb2 << 8) + (ih << 4) + iw;
    unsigned short* dst = o_ws + ((size_t)win * 64 + h * 8 + r) * 256 + s * 32 + hf * 16;
    #pragma unroll
    for (int jj = 0; jj < 2; ++jj) {
        uint4 v = make_uint4(pk2c(o[jj * 8 + 0], o[jj * 8 + 1]), pk2c(o[jj * 8 + 2], o[jj * 8 + 3]),
                             pk2c(o[jj * 8 + 4], o[jj * 8 + 5]), pk2c(o[jj * 8 + 6], o[jj * 8 + 7]));
        *(uint4*)(dst + jj * 8) = v;
    }
}

// ---- k2: out-projection + bias + output scatter (32KB LDS, two y half-passes)
__global__ __launch_bounds__(512, 6) void outproj_kernel(
        const unsigned short* __restrict__ o_ws, const unsigned short* __restrict__ wo,
        const float* __restrict__ b_out, float* __restrict__ out) {
    __shared__ unsigned char lds[32768];
    const int tid = threadIdx.x;
    const int bid = blockIdx.x;
    const int b  = bid >> 8;
    const int ih = (bid >> 4) & 15;
    const int iw = bid & 15;

    {
        const unsigned char* src = (const unsigned char*)(o_ws + (size_t)bid * 16384);
        #pragma unroll
        for (int it = 0; it < 4; ++it) {
            int q = it * 512 + tid;            // 16-byte chunk id, 2048 total
            int np = q >> 5;                   // row n'
            int slot = (q & 31) ^ (np & 7);
            *(bf16x8*)(lds + np * 512 + (slot << 4)) = *(const bf16x8*)(src + q * 16);
        }
    }
    __syncthreads();

    const int lane = tid & 63;
    const int wave = tid >> 6;
    const int lrow = lane & 15;
    const int lk   = lane >> 4;
    const int j0 = wave * 32;

    f32x4 acc[4][2];
    #pragma unroll
    for (int mt = 0; mt < 4; ++mt)
        #pragma unroll
        for (int nt = 0; nt < 2; ++nt)
            acc[mt][nt] = (f32x4){0.f, 0.f, 0.f, 0.f};
    #pragma unroll
    for (int k = 0; k < 8; ++k) {
        bf16x8 a[4], bb[2];
        #pragma unroll
        for (int mt = 0; mt < 4; ++mt) {
            int t = mt * 16 + lrow;
            int slot = (k * 4 + lk) ^ (t & 7);
            a[mt] = *(const bf16x8*)(lds + t * 512 + (slot << 4));
        }
        #pragma unroll
        for (int nt = 0; nt < 2; ++nt) {
            int j = j0 + nt * 16 + lrow;
            bb[nt] = *(const bf16x8*)((const unsigned char*)wo + (size_t)j * 512 + k * 64 + lk * 16);
        }
        #pragma unroll
        for (int mt = 0; mt < 4; ++mt)
            #pragma unroll
            for (int nt = 0; nt < 2; ++nt)
                acc[mt][nt] = __builtin_amdgcn_mfma_f32_16x16x32_bf16(a[mt], bb[nt], acc[mt][nt], 0, 0, 0);
    }
    float bias[2];
    #pragma unroll
    for (int nt = 0; nt < 2; ++nt) bias[nt] = b_out[j0 + nt * 16 + lrow];
    __syncthreads();   // out2 tile dead; reuse LDS for fp32 y (two 128-col halves)

    const size_t obase = ((size_t)b * 256) * 16384 + (size_t)(iw * 8) * 128 + ih * 8;
    #pragma unroll
    for (int half = 0; half < 2; ++half) {
        if ((wave >> 2) == half) {
            int jl = (wave & 3) * 32;
            #pragma unroll
            for (int mt = 0; mt < 4; ++mt)
                #pragma unroll
                for (int nt = 0; nt < 2; ++nt)
                    #pragma unroll
                    for (int i = 0; i < 4; ++i) {
                        int t = mt * 16 + lk * 4 + i;
                        int el = jl + nt * 16 + lrow;      // 0..127
                        int sl = (el >> 2) ^ (t & 7);
                        *(float*)(lds + t * 512 + (sl << 4) + (el & 3) * 4) = acc[mt][nt][i] + bias[nt];
                    }
        }
        __syncthreads();
        #pragma unroll
        for (int it = 0; it < 2; ++it) {
            int idx = it * 512 + tid;              // 0..1023
            int el = idx >> 3, sp = idx & 7;       // el 0..127
            float vals[8];
            #pragma unroll
            for (int rp = 0; rp < 8; ++rp) {
                int t = rp * 8 + sp;
                int sl = (el >> 2) ^ (t & 7);
                vals[rp] = *(const float*)(lds + t * 512 + (sl << 4) + (el & 3) * 4);
            }
            float* po = out + obase + (size_t)(half * 128 + el) * 16384 + sp * 128;
            *(float4*)po       = make_float4(vals[0], vals[1], vals[2], vals[3]);
            *(float4*)(po + 4) = make_float4(vals[4], vals[5], vals[6], vals[7]);
        }
        __syncthreads();
    }
}

extern "C" void kernel_launch(void* const* d_in, const int* in_sizes, int n_in,
                              void* d_out, int out_size, void* d_ws, size_t ws_size,
                              hipStream_t stream) {
    const float* x     = (const float*)d_in[0];
    const float* w_qkv = (const float*)d_in[1];
    const float* w_out = (const float*)d_in[2];
    const float* b_out = (const float*)d_in[3];
    float* out = (float*)d_out;

    const size_t QKV_BYTES = 201326592;   // 96 chunks x 131072 tokens x 16 B
    const size_t O_BYTES   = 67108864;    // 2048 x 64 x 256 x 2

    unsigned short* qkv2 = (unsigned short*)d_ws;
    unsigned short* o_ws = (unsigned short*)((char*)d_ws + QKV_BYTES);
    unsigned short* wq   = (unsigned short*)((char*)d_ws + QKV_BYTES + O_BYTES);
    unsigned short* wo   = wq + 196608;

    wconv_kernel<<<dim3(1024), dim3(256), 0, stream>>>(w_qkv, w_out, wq, wo);
    qkv_gemm_kernel<<<dim3(2048), dim3(256), 0, stream>>>(x, wq, qkv2);
    attn_kernel<<<dim3(8192), dim3(256), 0, stream>>>(qkv2, o_ws);
    outproj_kernel<<<dim3(2048), dim3(512), 0, stream>>>(o_ws, wo, b_out, out);
}

// Round 8
// 281.440 us; speedup vs baseline: 1.6253x; 1.6253x over previous
//
#include <hip/hip_runtime.h>

#define SCALE 0.17677669529663687f

typedef __attribute__((ext_vector_type(8))) short bf16x8;
typedef __attribute__((ext_vector_type(4))) float f32x4;

__device__ __forceinline__ unsigned short f2bf(float f) {
    unsigned u = __float_as_uint(f);
    u += 0x7FFFu + ((u >> 16) & 1u);   // round-to-nearest-even
    return (unsigned short)(u >> 16);
}
__device__ __forceinline__ float bf2f(unsigned short s) {
    return __uint_as_float(((unsigned)s) << 16);
}
// pack two f32 -> u32 of 2 bf16 (lo = a, hi = b), RNE, pure C (NOTE: inline-asm
// v_cvt_pk_bf16_f32 produced NaNs in round 4 -- do not reintroduce without isolation)
__device__ __forceinline__ unsigned pk2c(float a, float b) {
    return (unsigned)f2bf(a) | ((unsigned)f2bf(b) << 16);
}

// ---------------- weights -> bf16 ----------------
__global__ __launch_bounds__(256) void wconv_kernel(
        const float* __restrict__ w_qkv, const float* __restrict__ w_out,
        unsigned short* __restrict__ wq, unsigned short* __restrict__ wo) {
    int idx = blockIdx.x * 256 + threadIdx.x;
    if (idx < 196608) wq[idx] = f2bf(w_qkv[idx]);
    else if (idx < 262144) wo[idx - 196608] = f2bf(w_out[idx - 196608]);
}

// ---- k1a: QKV GEMM (round-3 proven structure: clean HBM traffic).
// block = 64 consecutive tokens, 512 threads (8 waves).
// A = x-tile in LDS (M=tokens), B = wq streamed from L2 (N=channels).
// D bounced through LDS -> wave-cooperative 1KB-contiguous global stores.
// LDS: [0,32768) x-tile 64tok x 256ch bf16 swizzled; [32768,65536) D bounce.
__global__ __launch_bounds__(512, 4) void qkv_gemm_kernel(
        const float* __restrict__ x, const unsigned short* __restrict__ wq,
        unsigned short* __restrict__ qkv_ws) {
    __shared__ unsigned char lds[65536];
    const int tid  = threadIdx.x;
    const int tb   = blockIdx.x << 6;      // 64 consecutive tokens
    const int b    = tb >> 14;
    const int hw0  = tb & 16383;
    const float* xb = x + (size_t)b * 4194304 + hw0;
    const int tok  = tid & 63;             // lane = token (coalesced 256B x reads)
    const int wave = tid >> 6;             // 8 waves x 32-channel staging slices

    // stage x -> LDS bf16 [token][ch] swizzled; pack 8 ch -> one ds_write_b128.
    #pragma unroll
    for (int cg = 0; cg < 4; ++cg) {
        const int c0 = wave * 32 + cg * 8;
        float f[8];
        #pragma unroll
        for (int e = 0; e < 8; ++e) f[e] = xb[(size_t)(c0 + e) * 16384 + tok];
        unsigned u0 = pk2c(f[0], f[1]), u1 = pk2c(f[2], f[3]);
        unsigned u2 = pk2c(f[4], f[5]), u3 = pk2c(f[6], f[7]);
        const int slot = (c0 >> 3) ^ (tok & 7);
        *(uint4*)(lds + tok * 512 + (slot << 4)) = make_uint4(u0, u1, u2, u3);
    }
    __syncthreads();

    const int lane = tid & 63;
    const int lrow = lane & 15, lk = lane >> 4;
    const int j0w = wave * 32;             // wave's 32-col slice within each 256-col pass

    for (int nb = 0; nb < 3; ++nb) {
        f32x4 acc[4][2];
        #pragma unroll
        for (int mt = 0; mt < 4; ++mt)
            #pragma unroll
            for (int nt = 0; nt < 2; ++nt)
                acc[mt][nt] = (f32x4){0.f, 0.f, 0.f, 0.f};
        #pragma unroll
        for (int k = 0; k < 8; ++k) {
            bf16x8 a[4], bb[2];
            #pragma unroll
            for (int mt = 0; mt < 4; ++mt) {
                int t = mt * 16 + lrow;
                int slot = (k * 4 + lk) ^ (t & 7);
                a[mt] = *(const bf16x8*)(lds + t * 512 + (slot << 4));
            }
            #pragma unroll
            for (int nt = 0; nt < 2; ++nt) {
                int j = nb * 256 + j0w + nt * 16 + lrow;
                bb[nt] = *(const bf16x8*)((const unsigned char*)wq + (size_t)j * 512 + k * 64 + lk * 16);
            }
            #pragma unroll
            for (int mt = 0; mt < 4; ++mt)
                #pragma unroll
                for (int nt = 0; nt < 2; ++nt)
                    acc[mt][nt] = __builtin_amdgcn_mfma_f32_16x16x32_bf16(a[mt], bb[nt], acc[mt][nt], 0, 0, 0);
        }
        // D-frags -> D-bounce LDS (bf16, swizzled). col=lane&15 (channel), row=lk*4+i (token)
        #pragma unroll
        for (int mt = 0; mt < 4; ++mt)
            #pragma unroll
            for (int nt = 0; nt < 2; ++nt)
                #pragma unroll
                for (int i = 0; i < 4; ++i) {
                    int t = mt * 16 + lk * 4 + i;
                    int ch = j0w + nt * 16 + lrow;
                    int slot = (ch >> 3) ^ (t & 7);
                    *(unsigned short*)(lds + 32768 + t * 512 + (slot << 4) + (ch & 7) * 2) = f2bf(acc[mt][nt][i]);
                }
        __syncthreads();
        // coop store: qkv_ws[token][nb*256 + ch], 1KB contiguous per wave instruction
        #pragma unroll
        for (int it = 0; it < 4; ++it) {
            int idx = it * 512 + tid;
            int t = idx >> 5, c = idx & 31;
            int slot = c ^ (t & 7);
            bf16x8 vch = *(const bf16x8*)(lds + 32768 + t * 512 + (slot << 4));
            *(bf16x8*)(qkv_ws + (size_t)(tb + t) * 768 + nb * 256 + c * 8) = vch;
        }
        __syncthreads();
    }
}

// ---- k1b: head-attention, no LDS (round-5 proven). 1 thread = (token, head, half-dim).
// block = 16 tokens x 8 heads x 2 halves = 256 threads. q/k/v from L1/L2.
__global__ __launch_bounds__(256, 4) void attn_kernel(
        const unsigned short* __restrict__ qkv_ws, unsigned short* __restrict__ o_ws) {
    const int tid = threadIdx.x;
    const int tok = (blockIdx.x << 4) + (tid >> 4);
    const int h   = (tid >> 1) & 7;
    const int hf  = tid & 1;
    const unsigned short* row = qkv_ws + (size_t)tok * 768;

    float q[16];
    #pragma unroll
    for (int jj = 0; jj < 2; ++jj) {
        bf16x8 v = *(const bf16x8*)(row + h * 32 + hf * 16 + jj * 8);
        #pragma unroll
        for (int e = 0; e < 8; ++e) q[jj * 8 + e] = bf2f((unsigned short)v[e]);
    }
    float dots[8];
    #pragma unroll
    for (int g = 0; g < 8; ++g) {
        float acc = 0.f;
        #pragma unroll
        for (int jj = 0; jj < 2; ++jj) {
            bf16x8 v = *(const bf16x8*)(row + 256 + g * 32 + hf * 16 + jj * 8);
            #pragma unroll
            for (int e = 0; e < 8; ++e) acc += q[jj * 8 + e] * bf2f((unsigned short)v[e]);
        }
        dots[g] = acc;
    }
    #pragma unroll
    for (int g = 0; g < 8; ++g)
        dots[g] = (dots[g] + __shfl_xor(dots[g], 1, 64)) * SCALE;
    float mx = dots[0];
    #pragma unroll
    for (int g = 1; g < 8; ++g) mx = fmaxf(mx, dots[g]);
    float sum = 0.f;
    #pragma unroll
    for (int g = 0; g < 8; ++g) { dots[g] = __expf(dots[g] - mx); sum += dots[g]; }
    const float inv = 1.f / sum;
    float o[16];
    #pragma unroll
    for (int d = 0; d < 16; ++d) o[d] = 0.f;
    #pragma unroll
    for (int g = 0; g < 8; ++g) {
        const float p = dots[g] * inv;
        #pragma unroll
        for (int jj = 0; jj < 2; ++jj) {
            bf16x8 v = *(const bf16x8*)(row + 512 + g * 32 + hf * 16 + jj * 8);
            #pragma unroll
            for (int e = 0; e < 8; ++e) o[jj * 8 + e] += p * bf2f((unsigned short)v[e]);
        }
    }
    // mixing fold: out2[win][n'=h*8+r][c'=s*32 + hf*16 + jj*8 + e]
    const int bb2 = tok >> 14, rem = tok & 16383;
    const int himg = rem >> 7, wimg = rem & 127;
    const int ih = himg >> 3, r = himg & 7;
    const int iw = wimg >> 3, s = wimg & 7;
    const int win = (bb2 << 8) + (ih << 4) + iw;
    unsigned short* dst = o_ws + ((size_t)win * 64 + h * 8 + r) * 256 + s * 32 + hf * 16;
    #pragma unroll
    for (int jj = 0; jj < 2; ++jj) {
        uint4 v = make_uint4(pk2c(o[jj * 8 + 0], o[jj * 8 + 1]), pk2c(o[jj * 8 + 2], o[jj * 8 + 3]),
                             pk2c(o[jj * 8 + 4], o[jj * 8 + 5]), pk2c(o[jj * 8 + 6], o[jj * 8 + 7]));
        *(uint4*)(dst + jj * 8) = v;
    }
}

// ---- k2: out-projection + bias + output scatter (32KB LDS, two y half-passes)
__global__ __launch_bounds__(512, 6) void outproj_kernel(
        const unsigned short* __restrict__ o_ws, const unsigned short* __restrict__ wo,
        const float* __restrict__ b_out, float* __restrict__ out) {
    __shared__ unsigned char lds[32768];
    const int tid = threadIdx.x;
    const int bid = blockIdx.x;
    const int b  = bid >> 8;
    const int ih = (bid >> 4) & 15;
    const int iw = bid & 15;

    {
        const unsigned char* src = (const unsigned char*)(o_ws + (size_t)bid * 16384);
        #pragma unroll
        for (int it = 0; it < 4; ++it) {
            int q = it * 512 + tid;            // 16-byte chunk id, 2048 total
            int np = q >> 5;                   // row n'
            int slot = (q & 31) ^ (np & 7);
            *(bf16x8*)(lds + np * 512 + (slot << 4)) = *(const bf16x8*)(src + q * 16);
        }
    }
    __syncthreads();

    const int lane = tid & 63;
    const int wave = tid >> 6;
    const int lrow = lane & 15;
    const int lk   = lane >> 4;
    const int j0 = wave * 32;

    f32x4 acc[4][2];
    #pragma unroll
    for (int mt = 0; mt < 4; ++mt)
        #pragma unroll
        for (int nt = 0; nt < 2; ++nt)
            acc[mt][nt] = (f32x4){0.f, 0.f, 0.f, 0.f};
    #pragma unroll
    for (int k = 0; k < 8; ++k) {
        bf16x8 a[4], bb[2];
        #pragma unroll
        for (int mt = 0; mt < 4; ++mt) {
            int t = mt * 16 + lrow;
            int slot = (k * 4 + lk) ^ (t & 7);
            a[mt] = *(const bf16x8*)(lds + t * 512 + (slot << 4));
        }
        #pragma unroll
        for (int nt = 0; nt < 2; ++nt) {
            int j = j0 + nt * 16 + lrow;
            bb[nt] = *(const bf16x8*)((const unsigned char*)wo + (size_t)j * 512 + k * 64 + lk * 16);
        }
        #pragma unroll
        for (int mt = 0; mt < 4; ++mt)
            #pragma unroll
            for (int nt = 0; nt < 2; ++nt)
                acc[mt][nt] = __builtin_amdgcn_mfma_f32_16x16x32_bf16(a[mt], bb[nt], acc[mt][nt], 0, 0, 0);
    }
    float bias[2];
    #pragma unroll
    for (int nt = 0; nt < 2; ++nt) bias[nt] = b_out[j0 + nt * 16 + lrow];
    __syncthreads();   // out2 tile dead; reuse LDS for fp32 y (two 128-col halves)

    const size_t obase = ((size_t)b * 256) * 16384 + (size_t)(iw * 8) * 128 + ih * 8;
    #pragma unroll
    for (int half = 0; half < 2; ++half) {
        if ((wave >> 2) == half) {
            int jl = (wave & 3) * 32;
            #pragma unroll
            for (int mt = 0; mt < 4; ++mt)
                #pragma unroll
                for (int nt = 0; nt < 2; ++nt)
                    #pragma unroll
                    for (int i = 0; i < 4; ++i) {
                        int t = mt * 16 + lk * 4 + i;
                        int el = jl + nt * 16 + lrow;      // 0..127
                        int sl = (el >> 2) ^ (t & 7);
                        *(float*)(lds + t * 512 + (sl << 4) + (el & 3) * 4) = acc[mt][nt][i] + bias[nt];
                    }
        }
        __syncthreads();
        #pragma unroll
        for (int it = 0; it < 2; ++it) {
            int idx = it * 512 + tid;              // 0..1023
            int el = idx >> 3, sp = idx & 7;       // el 0..127
            float vals[8];
            #pragma unroll
            for (int rp = 0; rp < 8; ++rp) {
                int t = rp * 8 + sp;
                int sl = (el >> 2) ^ (t & 7);
                vals[rp] = *(const float*)(lds + t * 512 + (sl << 4) + (el & 3) * 4);
            }
            float* po = out + obase + (size_t)(half * 128 + el) * 16384 + sp * 128;
            *(float4*)po       = make_float4(vals[0], vals[1], vals[2], vals[3]);
            *(float4*)(po + 4) = make_float4(vals[4], vals[5], vals[6], vals[7]);
        }
        __syncthreads();
    }
}

extern "C" void kernel_launch(void* const* d_in, const int* in_sizes, int n_in,
                              void* d_out, int out_size, void* d_ws, size_t ws_size,
                              hipStream_t stream) {
    const float* x     = (const float*)d_in[0];
    const float* w_qkv = (const float*)d_in[1];
    const float* w_out = (const float*)d_in[2];
    const float* b_out = (const float*)d_in[3];
    float* out = (float*)d_out;

    const size_t QKV_BYTES = 201326592;   // 131072 x 768 x 2
    const size_t O_BYTES   = 67108864;    // 2048 x 64 x 256 x 2

    unsigned short* qkv_ws = (unsigned short*)d_ws;
    unsigned short* o_ws   = (unsigned short*)((char*)d_ws + QKV_BYTES);
    unsigned short* wq     = (unsigned short*)((char*)d_ws + QKV_BYTES + O_BYTES);
    unsigned short* wo     = wq + 196608;

    wconv_kernel<<<dim3(1024), dim3(256), 0, stream>>>(w_qkv, w_out, wq, wo);
    qkv_gemm_kernel<<<dim3(2048), dim3(512), 0, stream>>>(x, wq, qkv_ws);
    attn_kernel<<<dim3(8192), dim3(256), 0, stream>>>(qkv_ws, o_ws);
    outproj_kernel<<<dim3(2048), dim3(512), 0, stream>>>(o_ws, wo, b_out, out);
}